// Round 1
// 542.467 us; speedup vs baseline: 1.0638x; 1.0638x over previous
//
#include <hip/hip_runtime.h>
#include <hip/hip_bf16.h>

// Problem constants (fixed shapes from setup_inputs)
constexpr int NB   = 4;      // batch
constexpr int SL   = 4096;   // sequence length
constexpr int DIMC = 1024;   // model dim
constexpr int NH   = 16;     // heads
constexpr int DHC  = 64;     // head dim
constexpr int NFC  = 64;     // random features
constexpr int NCHK = 8;      // L-chunks for kv partial accumulation (512 tokens each)
constexpr int NCHQ = 32;     // L-chunks for phi
constexpr int LCQ  = SL / NCHQ;  // 128
constexpr float FEPS = 1e-6f;

typedef __attribute__((ext_vector_type(8))) short bf16x8_t;  // 8 bf16 (4 VGPRs)
typedef __attribute__((ext_vector_type(4))) float f32x4_t;   // MFMA accumulator
typedef __attribute__((ext_vector_type(4))) short s16x4_t;

// async global->LDS, 16 B per lane; LDS dest = wave-uniform base + lane*16
__device__ __forceinline__ void load_lds_16B(const short* g, short* l) {
  __builtin_amdgcn_global_load_lds(
      (__attribute__((address_space(1))) void*)(g),
      (__attribute__((address_space(3))) void*)(l), 16, 0, 0);
}

// ---------------------------------------------------------------------------
// fp32 -> bf16 cast (n divisible by 1024). 4 elements/thread.
// ---------------------------------------------------------------------------
__global__ __launch_bounds__(256) void cast_f32_to_bf16(
    const float* __restrict__ in, short* __restrict__ out, int n)
{
  const int i = (blockIdx.x * 256 + threadIdx.x) * 4;
  if (i >= n) return;
  const f32x4_t v = *(const f32x4_t*)(in + i);
  s16x4_t o;
#pragma unroll
  for (int j = 0; j < 4; j++) {
    __hip_bfloat16 h = __float2bfloat16(v[j]);
    o[j] = *(short*)&h;
  }
  *(s16x4_t*)(out + i) = o;
}

// ---------------------------------------------------------------------------
// W0 transposed per head, split bf16 hi/lo: W0T[h][f][dh]
// ---------------------------------------------------------------------------
__global__ __launch_bounds__(256) void prep_w0t_kernel(
    const float* __restrict__ Wrf, short* __restrict__ Whi, short* __restrict__ Wlo)
{
  const int h = blockIdx.x;
  for (int t = threadIdx.x; t < 4096; t += 256) {
    const int f = t >> 6, dh = t & 63;
    const float w = Wrf[(size_t)h * 4096 + dh * 64 + f];
    __hip_bfloat16 hi = __float2bfloat16(w);
    const float rem = w - __bfloat162float(hi);
    __hip_bfloat16 lo = __float2bfloat16(rem);
    Whi[(size_t)h * 4096 + t] = *(short*)&hi;
    Wlo[(size_t)h * 4096 + t] = *(short*)&lo;
  }
}

// ---------------------------------------------------------------------------
// LDS-staged GEMM (m97 structure): C[M,1024] = A[M,1024] @ W[1024,1024]^T + bias
// 128x128 block tile, BK=64, global_load_lds width=16, XOR-16B-chunk swizzle.
// MODE 0: fp32 C.  MODE 1: bf16 C.
// MODE 3: C as bf16 hi (C0) + lo (C1) + ksq[row][head] = sum_d val^2
// MODE 4: C as bf16 hi (C0) + lo (C1) only
// MODE 5: transposed bf16 output vT[(b*NH+h)*64 + d][swz(l)] (operand-swapped
//         MFMA so the output-tile fragment is C^T; XOR-16B-chunk swizzle on the
//         l-within-128 position baked into the global layout so consumers can
//         global_load_lds linearly and ds_read_b128 conflict-free).
// grid: (M/128, 8), block 256 (4 waves; wave = 64x64 quadrant)
// ---------------------------------------------------------------------------
template <int MODE>
__global__ __launch_bounds__(256) void gemm_lds_kernel(
    const short* __restrict__ A, const short* __restrict__ W,
    const float* __restrict__ bias, void* __restrict__ C0,
    void* __restrict__ C1, float* __restrict__ Ks)
{
  constexpr int K = 1024, N = 1024;
  const int lane = threadIdx.x & 63;
  const int wid  = threadIdx.x >> 6;
  const int sub  = lane & 15;
  const int quad = lane >> 4;
  const int wr   = (wid >> 1) * 64;
  const int wc   = (wid & 1) * 64;
  const int row0 = blockIdx.x * 128;
  const int col0 = blockIdx.y * 128;

  __shared__ short As[128 * 64];  // 16 KiB, row = 128 B (8 x 16B chunks)
  __shared__ short Bs[128 * 64];

  f32x4_t acc[4][4] = {};

  const int srow = lane >> 3;
  for (int k0 = 0; k0 < K; k0 += 64) {
#pragma unroll
    for (int t = 0; t < 4; t++) {
      const int R   = wid * 32 + t * 8;
      const int row = R + srow;
      const int c   = (lane & 7) ^ (row & 7);
      load_lds_16B(A + (size_t)(row0 + row) * K + k0 + c * 8, As + R * 64);
      load_lds_16B(W + (size_t)(col0 + row) * K + k0 + c * 8, Bs + R * 64);
    }
    __syncthreads();

    bf16x8_t a[2][4], b[2][4];
#pragma unroll
    for (int ks = 0; ks < 2; ks++) {
#pragma unroll
      for (int i = 0; i < 4; i++) {
        const int ra = wr + i * 16 + sub;
        a[ks][i] = *(const bf16x8_t*)(As + ra * 64 + (((ks * 4 + quad) ^ (ra & 7)) * 8));
        const int rb = wc + i * 16 + sub;
        b[ks][i] = *(const bf16x8_t*)(Bs + rb * 64 + (((ks * 4 + quad) ^ (rb & 7)) * 8));
      }
    }
#pragma unroll
    for (int ks = 0; ks < 2; ks++)
#pragma unroll
      for (int i = 0; i < 4; i++)
#pragma unroll
        for (int j = 0; j < 4; j++) {
          if constexpr (MODE == 5)
            acc[i][j] = __builtin_amdgcn_mfma_f32_16x16x32_bf16(b[ks][j], a[ks][i], acc[i][j], 0, 0, 0);
          else
            acc[i][j] = __builtin_amdgcn_mfma_f32_16x16x32_bf16(a[ks][i], b[ks][j], acc[i][j], 0, 0, 0);
        }
    __syncthreads();
  }

  const int rb0 = row0 + wr;
  const int cb0 = col0 + wc;
  if constexpr (MODE == 3 || MODE == 4) {
    __hip_bfloat16* chi = (__hip_bfloat16*)C0;
    __hip_bfloat16* clo = (__hip_bfloat16*)C1;
    float s[4][4];
#pragma unroll
    for (int i = 0; i < 4; i++)
#pragma unroll
      for (int r = 0; r < 4; r++) s[i][r] = 0.f;
#pragma unroll
    for (int j = 0; j < 4; j++) {
      const int col = cb0 + j * 16 + sub;
      const float bv = bias[col];
#pragma unroll
      for (int i = 0; i < 4; i++) {
        const int row = rb0 + i * 16 + quad * 4;
#pragma unroll
        for (int r = 0; r < 4; r++) {
          const float val = acc[i][j][r] + bv;
          const __hip_bfloat16 hi = __float2bfloat16(val);
          const float rem = val - __bfloat162float(hi);
          chi[(size_t)(row + r) * N + col] = hi;
          clo[(size_t)(row + r) * N + col] = __float2bfloat16(rem);
          if constexpr (MODE == 3) s[i][r] = fmaf(val, val, s[i][r]);
        }
      }
    }
    if constexpr (MODE == 3) {
      const int head = cb0 >> 6;  // wave's 64 cols = exactly one head
#pragma unroll
      for (int o = 1; o < 16; o <<= 1)
#pragma unroll
        for (int i = 0; i < 4; i++)
#pragma unroll
          for (int r = 0; r < 4; r++) s[i][r] += __shfl_xor(s[i][r], o);
      if (sub == 0) {
#pragma unroll
        for (int i = 0; i < 4; i++)
#pragma unroll
          for (int r = 0; r < 4; r++)
            Ks[(size_t)(rb0 + i * 16 + quad * 4 + r) * NH + head] = s[i][r];
      }
    }
  } else if constexpr (MODE == 5) {
    // acc[i][j][r] (swapped mfma) = C[ row(token) = rb0+i*16+sub ]
    //                                [ col       = cb0+j*16+quad*4+r ]
    __hip_bfloat16* vT = (__hip_bfloat16*)C0;
    const int bb    = row0 >> 12;          // batch (4096 rows per batch)
    const int lbase = rb0 - (bb << 12);    // token-within-batch base
#pragma unroll
    for (int j = 0; j < 4; j++) {
#pragma unroll
      for (int r = 0; r < 4; r++) {
        const int col = cb0 + j * 16 + quad * 4 + r;
        const int h = col >> 6, d = col & 63;
        const float bv = bias[col];
        const size_t rowbase = ((size_t)((bb * NH + h) * 64 + d)) * (size_t)SL;
#pragma unroll
        for (int i = 0; i < 4; i++) {
          const int l = lbase + i * 16 + sub;
          const int pos = (l & ~127) | (((((l >> 3) & 15) ^ (d & 15)) << 3) | (l & 7));
          vT[rowbase + pos] = __float2bfloat16(acc[i][j][r] + bv);
        }
      }
    }
  } else {
#pragma unroll
    for (int j = 0; j < 4; j++) {
      const int col = cb0 + j * 16 + sub;
      const float bv = bias[col];
#pragma unroll
      for (int i = 0; i < 4; i++) {
        const int row = rb0 + i * 16 + quad * 4;
#pragma unroll
        for (int r = 0; r < 4; r++) {
          const float val = acc[i][j][r] + bv;
          if constexpr (MODE == 0)
            ((float*)C0)[(size_t)(row + r) * N + col] = val;
          else
            ((__hip_bfloat16*)C0)[(size_t)(row + r) * N + col] = __float2bfloat16(val);
        }
      }
    }
  }
}

// ---------------------------------------------------------------------------
// feat_gemm: out[tok][h*64+f] = sum_dh in[tok][h*64+dh] * W0[h][dh][f]
// in given as bf16 hi+lo split; 3-term hi/lo MFMA for ~fp32 precision.
// grid: (NTOK/128, NH), block 256; wave handles 32 tokens.
// ---------------------------------------------------------------------------
__global__ __launch_bounds__(256) void feat_gemm_kernel(
    const short* __restrict__ xhi, const short* __restrict__ xlo,
    const short* __restrict__ Whi, const short* __restrict__ Wlo,
    float* __restrict__ outlog)
{
  const int lane = threadIdx.x & 63, wid = threadIdx.x >> 6;
  const int sub = lane & 15, quad = lane >> 4;
  const int h = blockIdx.y;
  const int tok0 = blockIdx.x * 128 + wid * 32;
  const short* Bh = Whi + (size_t)h * 4096;
  const short* Bl = Wlo + (size_t)h * 4096;

  f32x4_t acc[2][4] = {};
#pragma unroll
  for (int ks = 0; ks < 2; ks++) {
    const int ko = ks * 32 + quad * 8;
    bf16x8_t ah[2], al[2], bh[4], bl[4];
#pragma unroll
    for (int i = 0; i < 2; i++) {
      const size_t base = (size_t)(tok0 + i * 16 + sub) * DIMC + h * 64 + ko;
      ah[i] = *(const bf16x8_t*)(xhi + base);
      al[i] = *(const bf16x8_t*)(xlo + base);
    }
#pragma unroll
    for (int j = 0; j < 4; j++) {
      const size_t base = (size_t)(j * 16 + sub) * 64 + ko;
      bh[j] = *(const bf16x8_t*)(Bh + base);
      bl[j] = *(const bf16x8_t*)(Bl + base);
    }
#pragma unroll
    for (int i = 0; i < 2; i++)
#pragma unroll
      for (int j = 0; j < 4; j++) {
        acc[i][j] = __builtin_amdgcn_mfma_f32_16x16x32_bf16(ah[i], bh[j], acc[i][j], 0, 0, 0);
        acc[i][j] = __builtin_amdgcn_mfma_f32_16x16x32_bf16(al[i], bh[j], acc[i][j], 0, 0, 0);
        acc[i][j] = __builtin_amdgcn_mfma_f32_16x16x32_bf16(ah[i], bl[j], acc[i][j], 0, 0, 0);
      }
  }
#pragma unroll
  for (int i = 0; i < 2; i++)
#pragma unroll
    for (int j = 0; j < 4; j++)
#pragma unroll
      for (int r = 0; r < 4; r++)
        outlog[(size_t)(tok0 + i * 16 + quad * 4 + r) * DIMC + h * 64 + j * 16 + sub] = acc[i][j][r];
}

// ---------------------------------------------------------------------------
// MFMA key summary. Per (b,h, chunk of 512 tokens):
//   w[l,f] = exp(klog[l,h,f] - 0.5*ksq[l,h])   (bf16 hi/lo in LDS, transposed)
//   N[f,d] += w^T @ vT  (MFMA, K = l), D[f] += w^T @ ones (same A-frags)
// vT global layout is pre-swizzled by gemm MODE 5, so staging is a LINEAR
// global_load_lds and all ds_read_b128 land on 8 distinct banks (2-way, free).
// grid: (NCHK=8, NH, NB), block 256 (4 waves; wave w owns f in [16w,16w+16)).
// ---------------------------------------------------------------------------
__global__ __launch_bounds__(256) void kv_summary_mfma(
    const float* __restrict__ klog, const float* __restrict__ ksq,
    const short* __restrict__ vT, float* __restrict__ pN, float* __restrict__ pD)
{
  const int chunk = blockIdx.x, h = blockIdx.y, b = blockIdx.z;
  const int tid  = threadIdx.x;
  const int lane = tid & 63, wid = tid >> 6;
  const int sub  = lane & 15, quad = lane >> 4;

  __shared__ short vTs[64 * 128];  // 16 KiB, row d = 256 B (16 x 16B chunks)
  __shared__ short wTh[64 * 128];  // 16 KiB, row f = 256 B
  __shared__ short wTl[64 * 128];  // 16 KiB

  f32x4_t accN[4] = {};
  f32x4_t accD = {};
  bf16x8_t bones;
#pragma unroll
  for (int e = 0; e < 8; e++) bones[e] = (sub == 0) ? (short)0x3F80 : (short)0;

  // w-phase mapping: thread pair per token (128 B of klog each)
  const int tw_t  = tid >> 1;          // 0..127 token-within-tile
  const int tw_f0 = (tid & 1) * 32;    // feature half

  const size_t vbase = ((size_t)((b * NH + h) * 64)) * (size_t)SL;
  const int fbase = (wid * 16 + sub) * 128;  // this wave's A-frag row base

  for (int it = 0; it < 4; ++it) {
    const int l0 = chunk * 512 + it * 128;

    // A) stage vT tile (swizzle already baked into global layout -> linear)
#pragma unroll
    for (int q = 0; q < 4; q++) {
      const int dbase = wid * 16 + q * 4;           // wave-uniform
      const int d = dbase + (lane >> 4);            // per-lane source row
      load_lds_16B(vT + vbase + (size_t)d * SL + l0 + (lane & 15) * 8,
                   vTs + dbase * 128);
    }

    // B) compute w = exp(klog - 0.5 ksq), write transposed hi/lo to LDS
    {
      const int tok = b * SL + l0 + tw_t;
      const float kq = 0.5f * ksq[tok * NH + h];
      const float* kr = klog + (size_t)tok * DIMC + h * 64 + tw_f0;
      f32x4_t kl[8];
#pragma unroll
      for (int v4 = 0; v4 < 8; v4++) kl[v4] = *(const f32x4_t*)(kr + v4 * 4);
#pragma unroll
      for (int v4 = 0; v4 < 8; v4++) {
#pragma unroll
        for (int e = 0; e < 4; e++) {
          const int f = tw_f0 + v4 * 4 + e;
          const float wv = __expf(kl[v4][e] - kq);
          const __hip_bfloat16 hi = __float2bfloat16(wv);
          const float rem = wv - __bfloat162float(hi);
          const __hip_bfloat16 lo = __float2bfloat16(rem);
          const int p = f * 128 + (((((tw_t >> 3) & 15) ^ (f & 15)) << 3) | (tw_t & 7));
          wTh[p] = *(const short*)&hi;
          wTl[p] = *(const short*)&lo;
        }
      }
    }
    __syncthreads();  // drains global_load_lds (vmcnt) + wT writes

    // C) MFMA: N[f,d] += w^T v ; D[f] += w^T 1
#pragma unroll
    for (int ks = 0; ks < 4; ks++) {
      const int ch = ks * 4 + quad;
      const bf16x8_t ah = *(const bf16x8_t*)(wTh + fbase + ((ch ^ sub) << 3));
      const bf16x8_t al = *(const bf16x8_t*)(wTl + fbase + ((ch ^ sub) << 3));
      accD = __builtin_amdgcn_mfma_f32_16x16x32_bf16(ah, bones, accD, 0, 0, 0);
      accD = __builtin_amdgcn_mfma_f32_16x16x32_bf16(al, bones, accD, 0, 0, 0);
#pragma unroll
      for (int j = 0; j < 4; j++) {
        const bf16x8_t bv = *(const bf16x8_t*)(vTs + (j * 16 + sub) * 128 + ((ch ^ sub) << 3));
        accN[j] = __builtin_amdgcn_mfma_f32_16x16x32_bf16(ah, bv, accN[j], 0, 0, 0);
        accN[j] = __builtin_amdgcn_mfma_f32_16x16x32_bf16(al, bv, accN[j], 0, 0, 0);
      }
    }
    __syncthreads();  // all reads done before next iteration restages
  }

  // write partials: pN[(bh,chunk)][f*64+d], pD[(bh,chunk)][f]
  const size_t pbase = (size_t)((b * NH + h) * NCHK + chunk);
#pragma unroll
  for (int j = 0; j < 4; j++)
#pragma unroll
    for (int r = 0; r < 4; r++)
      pN[pbase * 4096 + (wid * 16 + quad * 4 + r) * 64 + j * 16 + sub] = accN[j][r];
  if (sub == 0) {
#pragma unroll
    for (int r = 0; r < 4; r++)
      pD[pbase * 64 + wid * 16 + quad * 4 + r] = accD[r];
  }
}

// ---------------------------------------------------------------------------
// Combine chunk partials; write N^T (normalized, bf16 hi/lo, [d][f]) and
// normalized D (fp32). grid: (NB*NH, 16), block 256.
// ---------------------------------------------------------------------------
__global__ __launch_bounds__(256) void combine_nd_kernel(
    const float* __restrict__ pN, const float* __restrict__ pD,
    short* __restrict__ NfTh, short* __restrict__ NfTl, float* __restrict__ Df)
{
  const int bh = blockIdx.x, seg = blockIdx.y;
  __shared__ float sInv;
  float dsum = 0.f;
  if (threadIdx.x < 64) {
    for (int c = 0; c < NCHK; c++)
      dsum += pD[(size_t)(bh * NCHK + c) * 64 + threadIdx.x];
    float s = dsum;
#pragma unroll
    for (int o = 32; o; o >>= 1) s += __shfl_xor(s, o);
    if (threadIdx.x == 0) sInv = 1.f / s;
  }
  __syncthreads();
  const float inv = sInv;
  if (seg == 0 && threadIdx.x < 64) Df[bh * 64 + threadIdx.x] = dsum * inv;
  const int t = seg * 256 + threadIdx.x;   // t = f*64 + d
  float acc = 0.f;
  for (int c = 0; c < NCHK; c++)
    acc += pN[((size_t)(bh * NCHK + c)) * 4096 + t];
  const float val = acc * inv;
  const int f = t >> 6, d = t & 63;
  const __hip_bfloat16 hi = __float2bfloat16(val);
  const float rem = val - __bfloat162float(hi);
  const __hip_bfloat16 lo = __float2bfloat16(rem);
  NfTh[(size_t)bh * 4096 + d * 64 + f] = *(const short*)&hi;
  NfTl[(size_t)bh * 4096 + d * 64 + f] = *(const short*)&lo;
}

// ---------------------------------------------------------------------------
// phi: per (l,h): max-shifted exp of qlog, write e as bf16 hi/lo (A-layout
// [token][h*64+f]) and fused scale s = 1/(dt + eps*se).
// grid: (NCHQ, NH, NB), block 256
// ---------------------------------------------------------------------------
__global__ __launch_bounds__(256) void phi_kernel(
    const float* __restrict__ qlog, const float* __restrict__ Df,
    short* __restrict__ ehi, short* __restrict__ elo, float* __restrict__ sbuf)
{
  const int chunk = blockIdx.x, h = blockIdx.y, b = blockIdx.z;
  const int lane = threadIdx.x & 63, wid = threadIdx.x >> 6;
  const float Dl = Df[(b * NH + h) * 64 + lane];

  const int l0 = chunk * LCQ;
  for (int li = wid; li < LCQ; li += 4) {
    const int token = b * SL + l0 + li;
    const size_t base = (size_t)token * DIMC + h * DHC;
    const float lg = qlog[base + lane];

    float mx = lg;
#pragma unroll
    for (int o = 32; o; o >>= 1) mx = fmaxf(mx, __shfl_xor(mx, o));
    const float e = __expf(lg - mx);
    float se = e, dt = e * Dl;
#pragma unroll
    for (int o = 32; o; o >>= 1) { se += __shfl_xor(se, o); dt += __shfl_xor(dt, o); }

    const __hip_bfloat16 hi = __float2bfloat16(e);
    const float rem = e - __bfloat162float(hi);
    const __hip_bfloat16 lo = __float2bfloat16(rem);
    ehi[base + lane] = *(const short*)&hi;
    elo[base + lane] = *(const short*)&lo;
    if (lane == 0) sbuf[token * NH + h] = 1.f / (dt + FEPS * se);
  }
}

// ---------------------------------------------------------------------------
// ctx = (e @ N^T) * s : per (b,h) GEMM, M=tokens, N=64 d, K=64 f, 3-term hi/lo
// grid: (NTOK/128, NH), block 256; wave handles 32 tokens.
// ---------------------------------------------------------------------------
__global__ __launch_bounds__(256) void ctx_gemm_kernel(
    const short* __restrict__ ehi, const short* __restrict__ elo,
    const short* __restrict__ NfTh, const short* __restrict__ NfTl,
    const float* __restrict__ sbuf, __hip_bfloat16* __restrict__ ctx)
{
  const int lane = threadIdx.x & 63, wid = threadIdx.x >> 6;
  const int sub = lane & 15, quad = lane >> 4;
  const int h = blockIdx.y;
  const int tok0 = blockIdx.x * 128 + wid * 32;
  const int b = blockIdx.x >> 5;  // 32 x-blocks per batch (SL/128)
  const short* Bh = NfTh + ((size_t)(b * NH + h)) * 4096;
  const short* Bl = NfTl + ((size_t)(b * NH + h)) * 4096;

  f32x4_t acc[2][4] = {};
#pragma unroll
  for (int ks = 0; ks < 2; ks++) {
    const int ko = ks * 32 + quad * 8;
    bf16x8_t ah[2], al[2], bh[4], bl[4];
#pragma unroll
    for (int i = 0; i < 2; i++) {
      const size_t base = (size_t)(tok0 + i * 16 + sub) * DIMC + h * 64 + ko;
      ah[i] = *(const bf16x8_t*)(ehi + base);
      al[i] = *(const bf16x8_t*)(elo + base);
    }
#pragma unroll
    for (int j = 0; j < 4; j++) {
      const size_t base = (size_t)(j * 16 + sub) * 64 + ko;
      bh[j] = *(const bf16x8_t*)(Bh + base);
      bl[j] = *(const bf16x8_t*)(Bl + base);
    }
#pragma unroll
    for (int i = 0; i < 2; i++)
#pragma unroll
      for (int j = 0; j < 4; j++) {
        acc[i][j] = __builtin_amdgcn_mfma_f32_16x16x32_bf16(ah[i], bh[j], acc[i][j], 0, 0, 0);
        acc[i][j] = __builtin_amdgcn_mfma_f32_16x16x32_bf16(al[i], bh[j], acc[i][j], 0, 0, 0);
        acc[i][j] = __builtin_amdgcn_mfma_f32_16x16x32_bf16(ah[i], bl[j], acc[i][j], 0, 0, 0);
      }
  }
#pragma unroll
  for (int i = 0; i < 2; i++)
#pragma unroll
    for (int r = 0; r < 4; r++) {
      const int token = tok0 + i * 16 + quad * 4 + r;
      const float sv = sbuf[token * NH + h];
#pragma unroll
      for (int j = 0; j < 4; j++)
        ctx[(size_t)token * DIMC + h * 64 + j * 16 + sub] =
            __float2bfloat16(acc[i][j][r] * sv);
    }
}

// ---------------------------------------------------------------------------
extern "C" void kernel_launch(void* const* d_in, const int* in_sizes, int n_in,
                              void* d_out, int out_size, void* d_ws, size_t ws_size,
                              hipStream_t stream) {
  (void)in_sizes; (void)n_in; (void)out_size; (void)ws_size;
  const float* x   = (const float*)d_in[0];
  const float* Wq  = (const float*)d_in[1];
  const float* bq  = (const float*)d_in[2];
  const float* Wk  = (const float*)d_in[3];
  const float* bk  = (const float*)d_in[4];
  const float* Wv  = (const float*)d_in[5];
  const float* bv  = (const float*)d_in[6];
  const float* Wo  = (const float*)d_in[7];
  const float* bo  = (const float*)d_in[8];
  const float* Wrf = (const float*)d_in[9];
  float* out = (float*)d_out;

  constexpr size_t MiB = 1u << 20;
  constexpr size_t KiB = 1u << 10;
  constexpr size_t NTOK = (size_t)NB * SL;   // 16384
  constexpr size_t XN   = NTOK * DIMC;
  constexpr size_t WN   = (size_t)DIMC * DIMC;

  char* ws = (char*)d_ws;
  short* xb   = (short*)(ws);                        // bf16 x, 32 MiB; later ctxb
  short* Wkb  = (short*)(ws + 32 * MiB);
  short* Wvb  = (short*)(ws + 34 * MiB);
  short* Wob  = (short*)(ws + 36 * MiB);
  short* Wqb  = (short*)(ws + 38 * MiB);
  short* W0Th = (short*)(ws + 40 * MiB);             // 128 KiB
  short* W0Tl = (short*)(ws + 40 * MiB + 128 * KiB); // 128 KiB
  float* ksq  = (float*)(ws + 41 * MiB);             // 1 MiB
  float* sbuf = (float*)(ws + 42 * MiB);             // 1 MiB
  float* pD   = (float*)(ws + 43 * MiB);             // 128 KiB (64*8*64 f32)
  short* NfTh = (short*)(ws + 43 * MiB + 512 * KiB); // 512 KiB
  short* NfTl = (short*)(ws + 44 * MiB);             // 512 KiB
  float* Df   = (float*)(ws + 44 * MiB + 512 * KiB); // 16 KiB
  float* klog = (float*)(ws + 45 * MiB);             // 64 MiB [45..109)
  __hip_bfloat16* khi = (__hip_bfloat16*)(ws + 109 * MiB);  // 32 MiB
  __hip_bfloat16* klo = (__hip_bfloat16*)(ws + 141 * MiB);  // 32 MiB
  short* vTb  = (short*)(ws + 173 * MiB);            // 32 MiB, vT[(b,h,d)][swz l]
  // overlays (all precede their overwrite in stream order):
  float* pN   = (float*)(ws + 109 * MiB);            // 8 MiB over khi (dead after feat_gemm k)
  __hip_bfloat16* qhi = (__hip_bfloat16*)(ws + 45 * MiB);   // over klog (dead after kv_summary)
  __hip_bfloat16* qlo = (__hip_bfloat16*)(ws + 77 * MiB);
  float* qlog = (float*)(ws + 141 * MiB);            // 64 MiB over klo+vTb (dead)
  short* ehi  = (short*)(ws + 45 * MiB);             // over qhi/qlo (dead after feat_gemm q)
  short* elo  = (short*)(ws + 77 * MiB);
  __hip_bfloat16* ctxb = (__hip_bfloat16*)xb;        // over xb (dead after q GEMM)

  const dim3 blk(256);

  cast_f32_to_bf16<<<dim3(XN / 1024), blk, 0, stream>>>(x, xb, (int)XN);
  cast_f32_to_bf16<<<dim3(WN / 1024), blk, 0, stream>>>(Wk, Wkb, (int)WN);
  cast_f32_to_bf16<<<dim3(WN / 1024), blk, 0, stream>>>(Wv, Wvb, (int)WN);
  cast_f32_to_bf16<<<dim3(WN / 1024), blk, 0, stream>>>(Wo, Wob, (int)WN);
  cast_f32_to_bf16<<<dim3(WN / 1024), blk, 0, stream>>>(Wq, Wqb, (int)WN);
  prep_w0t_kernel<<<dim3(NH), blk, 0, stream>>>(Wrf, W0Th, W0Tl);

  const dim3 gg(NTOK / 128, DIMC / 128);
  gemm_lds_kernel<3><<<gg, blk, 0, stream>>>(xb, Wkb, bk, khi, klo, ksq);
  gemm_lds_kernel<5><<<gg, blk, 0, stream>>>(xb, Wvb, bv, vTb, nullptr, nullptr);

  feat_gemm_kernel<<<dim3(NTOK / 128, NH), blk, 0, stream>>>(
      (const short*)khi, (const short*)klo, W0Th, W0Tl, klog);

  kv_summary_mfma<<<dim3(NCHK, NH, NB), blk, 0, stream>>>(klog, ksq, vTb, pN, pD);
  combine_nd_kernel<<<dim3(NB * NH, 16), blk, 0, stream>>>(pN, pD, NfTh, NfTl, Df);

  gemm_lds_kernel<4><<<gg, blk, 0, stream>>>(xb, Wqb, bq, qhi, qlo, nullptr);
  feat_gemm_kernel<<<dim3(NTOK / 128, NH), blk, 0, stream>>>(
      (const short*)qhi, (const short*)qlo, W0Th, W0Tl, qlog);
  phi_kernel<<<dim3(NCHQ, NH, NB), blk, 0, stream>>>(qlog, Df, ehi, elo, sbuf);
  ctx_gemm_kernel<<<dim3(NTOK / 128, NH), blk, 0, stream>>>(
      ehi, elo, NfTh, NfTl, sbuf, ctxb);

  gemm_lds_kernel<0><<<gg, blk, 0, stream>>>((const short*)ctxb, Wob, bo, out, nullptr, nullptr);
}

// Round 2
// 491.104 us; speedup vs baseline: 1.1750x; 1.1046x over previous
//
#include <hip/hip_runtime.h>
#include <hip/hip_bf16.h>

// Problem constants (fixed shapes from setup_inputs)
constexpr int NB   = 4;      // batch
constexpr int SL   = 4096;   // sequence length
constexpr int DIMC = 1024;   // model dim
constexpr int NH   = 16;     // heads
constexpr int DHC  = 64;     // head dim
constexpr int NFC  = 64;     // random features
constexpr int NCHK = 8;      // L-chunks for kv partial accumulation (512 tokens each)
constexpr float FEPS = 1e-6f;

typedef __attribute__((ext_vector_type(8))) short bf16x8_t;  // 8 bf16 (4 VGPRs)
typedef __attribute__((ext_vector_type(4))) float f32x4_t;   // MFMA accumulator
typedef __attribute__((ext_vector_type(4))) short s16x4_t;

// async global->LDS, 16 B per lane; LDS dest = wave-uniform base + lane*16
__device__ __forceinline__ void load_lds_16B(const short* g, short* l) {
  __builtin_amdgcn_global_load_lds(
      (__attribute__((address_space(1))) void*)(g),
      (__attribute__((address_space(3))) void*)(l), 16, 0, 0);
}

// ---------------------------------------------------------------------------
// fp32 -> bf16 cast (n divisible by 1024). 4 elements/thread.
// ---------------------------------------------------------------------------
__global__ __launch_bounds__(256) void cast_f32_to_bf16(
    const float* __restrict__ in, short* __restrict__ out, int n)
{
  const int i = (blockIdx.x * 256 + threadIdx.x) * 4;
  if (i >= n) return;
  const f32x4_t v = *(const f32x4_t*)(in + i);
  s16x4_t o;
#pragma unroll
  for (int j = 0; j < 4; j++) {
    __hip_bfloat16 h = __float2bfloat16(v[j]);
    o[j] = *(short*)&h;
  }
  *(s16x4_t*)(out + i) = o;
}

// ---------------------------------------------------------------------------
// W0 transposed per head, split bf16 hi/lo: W0T[h][f][dh]
// ---------------------------------------------------------------------------
__global__ __launch_bounds__(256) void prep_w0t_kernel(
    const float* __restrict__ Wrf, short* __restrict__ Whi, short* __restrict__ Wlo)
{
  const int h = blockIdx.x;
  for (int t = threadIdx.x; t < 4096; t += 256) {
    const int f = t >> 6, dh = t & 63;
    const float w = Wrf[(size_t)h * 4096 + dh * 64 + f];
    __hip_bfloat16 hi = __float2bfloat16(w);
    const float rem = w - __bfloat162float(hi);
    __hip_bfloat16 lo = __float2bfloat16(rem);
    Whi[(size_t)h * 4096 + t] = *(short*)&hi;
    Wlo[(size_t)h * 4096 + t] = *(short*)&lo;
  }
}

// ---------------------------------------------------------------------------
// Fused weight: Wqf[h*64+f][c] = sum_d Wq[h*64+d][c] * W0[h][d][f]  (fp32),
// split to bf16 hi/lo. bqf[h*64+f] = sum_d bq[h*64+d]*W0[h][d][f] (fp32).
// grid (NH, 16 c-blocks), block 256.
// ---------------------------------------------------------------------------
__global__ __launch_bounds__(256) void fuse_w0_kernel(
    const float* __restrict__ Wq, const float* __restrict__ bq,
    const float* __restrict__ Wrf,
    short* __restrict__ Wfh, short* __restrict__ Wfl, float* __restrict__ bqf)
{
  const int h = blockIdx.x, cb = blockIdx.y;
  __shared__ float sWq[64][64];  // [d][cc]
  __shared__ float sW0[64][64];  // [d][f]
  for (int idx = threadIdx.x; idx < 4096; idx += 256) {
    const int d = idx >> 6, e = idx & 63;
    sWq[d][e] = Wq[(size_t)(h * 64 + d) * 1024 + cb * 64 + e];
    sW0[d][e] = Wrf[(size_t)h * 4096 + d * 64 + e];
  }
  __syncthreads();
  for (int idx = threadIdx.x; idx < 4096; idx += 256) {
    const int f = idx >> 6, cc = idx & 63;
    float acc = 0.f;
#pragma unroll
    for (int d = 0; d < 64; d++) acc = fmaf(sWq[d][cc], sW0[d][f], acc);
    const __hip_bfloat16 hi = __float2bfloat16(acc);
    const float rem = acc - __bfloat162float(hi);
    const __hip_bfloat16 lo = __float2bfloat16(rem);
    Wfh[(size_t)(h * 64 + f) * 1024 + cb * 64 + cc] = *(const short*)&hi;
    Wfl[(size_t)(h * 64 + f) * 1024 + cb * 64 + cc] = *(const short*)&lo;
  }
  if (cb == 0 && threadIdx.x < 64) {
    const int f = threadIdx.x;
    float acc = 0.f;
#pragma unroll
    for (int d = 0; d < 64; d++) acc = fmaf(bq[h * 64 + d], sW0[d][f], acc);
    bqf[h * 64 + f] = acc;
  }
}

// ---------------------------------------------------------------------------
// LDS-staged GEMM (m97 structure): C[M,1024] = A[M,1024] @ W[1024,1024]^T + bias
// 128x128 block tile, BK=64, global_load_lds width=16, XOR-16B-chunk swizzle.
// MODE 0: fp32 C.
// MODE 3: C as bf16 hi (C0) + lo (C1) + ksq[row][head] = sum_d val^2
// MODE 5: transposed bf16 output vT[(b*NH+h)*64 + d][swz(l)] (operand-swapped
//         MFMA so the output-tile fragment is C^T; XOR-16B-chunk swizzle on the
//         l-within-128 position baked into the global layout so consumers can
//         global_load_lds linearly and ds_read_b128 conflict-free).
// grid: (M/128, 8), block 256 (4 waves; wave = 64x64 quadrant)
// ---------------------------------------------------------------------------
template <int MODE>
__global__ __launch_bounds__(256) void gemm_lds_kernel(
    const short* __restrict__ A, const short* __restrict__ W,
    const float* __restrict__ bias, void* __restrict__ C0,
    void* __restrict__ C1, float* __restrict__ Ks)
{
  constexpr int K = 1024, N = 1024;
  const int lane = threadIdx.x & 63;
  const int wid  = threadIdx.x >> 6;
  const int sub  = lane & 15;
  const int quad = lane >> 4;
  const int wr   = (wid >> 1) * 64;
  const int wc   = (wid & 1) * 64;
  const int row0 = blockIdx.x * 128;
  const int col0 = blockIdx.y * 128;

  __shared__ short As[128 * 64];  // 16 KiB, row = 128 B (8 x 16B chunks)
  __shared__ short Bs[128 * 64];

  f32x4_t acc[4][4] = {};

  const int srow = lane >> 3;
  for (int k0 = 0; k0 < K; k0 += 64) {
#pragma unroll
    for (int t = 0; t < 4; t++) {
      const int R   = wid * 32 + t * 8;
      const int row = R + srow;
      const int c   = (lane & 7) ^ (row & 7);
      load_lds_16B(A + (size_t)(row0 + row) * K + k0 + c * 8, As + R * 64);
      load_lds_16B(W + (size_t)(col0 + row) * K + k0 + c * 8, Bs + R * 64);
    }
    __syncthreads();

    bf16x8_t a[2][4], b[2][4];
#pragma unroll
    for (int ks = 0; ks < 2; ks++) {
#pragma unroll
      for (int i = 0; i < 4; i++) {
        const int ra = wr + i * 16 + sub;
        a[ks][i] = *(const bf16x8_t*)(As + ra * 64 + (((ks * 4 + quad) ^ (ra & 7)) * 8));
        const int rb = wc + i * 16 + sub;
        b[ks][i] = *(const bf16x8_t*)(Bs + rb * 64 + (((ks * 4 + quad) ^ (rb & 7)) * 8));
      }
    }
#pragma unroll
    for (int ks = 0; ks < 2; ks++)
#pragma unroll
      for (int i = 0; i < 4; i++)
#pragma unroll
        for (int j = 0; j < 4; j++) {
          if constexpr (MODE == 5)
            acc[i][j] = __builtin_amdgcn_mfma_f32_16x16x32_bf16(b[ks][j], a[ks][i], acc[i][j], 0, 0, 0);
          else
            acc[i][j] = __builtin_amdgcn_mfma_f32_16x16x32_bf16(a[ks][i], b[ks][j], acc[i][j], 0, 0, 0);
        }
    __syncthreads();
  }

  const int rb0 = row0 + wr;
  const int cb0 = col0 + wc;
  if constexpr (MODE == 3) {
    __hip_bfloat16* chi = (__hip_bfloat16*)C0;
    __hip_bfloat16* clo = (__hip_bfloat16*)C1;
    float s[4][4];
#pragma unroll
    for (int i = 0; i < 4; i++)
#pragma unroll
      for (int r = 0; r < 4; r++) s[i][r] = 0.f;
#pragma unroll
    for (int j = 0; j < 4; j++) {
      const int col = cb0 + j * 16 + sub;
      const float bv = bias[col];
#pragma unroll
      for (int i = 0; i < 4; i++) {
        const int row = rb0 + i * 16 + quad * 4;
#pragma unroll
        for (int r = 0; r < 4; r++) {
          const float val = acc[i][j][r] + bv;
          const __hip_bfloat16 hi = __float2bfloat16(val);
          const float rem = val - __bfloat162float(hi);
          chi[(size_t)(row + r) * N + col] = hi;
          clo[(size_t)(row + r) * N + col] = __float2bfloat16(rem);
          s[i][r] = fmaf(val, val, s[i][r]);
        }
      }
    }
    {
      const int head = cb0 >> 6;  // wave's 64 cols = exactly one head
#pragma unroll
      for (int o = 1; o < 16; o <<= 1)
#pragma unroll
        for (int i = 0; i < 4; i++)
#pragma unroll
          for (int r = 0; r < 4; r++) s[i][r] += __shfl_xor(s[i][r], o);
      if (sub == 0) {
#pragma unroll
        for (int i = 0; i < 4; i++)
#pragma unroll
          for (int r = 0; r < 4; r++)
            Ks[(size_t)(rb0 + i * 16 + quad * 4 + r) * NH + head] = s[i][r];
      }
    }
  } else if constexpr (MODE == 5) {
    // acc[i][j][r] (swapped mfma) = C[ row(token) = rb0+i*16+sub ]
    //                                [ col       = cb0+j*16+quad*4+r ]
    __hip_bfloat16* vT = (__hip_bfloat16*)C0;
    const int bb    = row0 >> 12;          // batch (4096 rows per batch)
    const int lbase = rb0 - (bb << 12);    // token-within-batch base
#pragma unroll
    for (int j = 0; j < 4; j++) {
#pragma unroll
      for (int r = 0; r < 4; r++) {
        const int col = cb0 + j * 16 + quad * 4 + r;
        const int h = col >> 6, d = col & 63;
        const float bv = bias[col];
        const size_t rowbase = ((size_t)((bb * NH + h) * 64 + d)) * (size_t)SL;
#pragma unroll
        for (int i = 0; i < 4; i++) {
          const int l = lbase + i * 16 + sub;
          const int pos = (l & ~127) | (((((l >> 3) & 15) ^ (d & 15)) << 3) | (l & 7));
          vT[rowbase + pos] = __float2bfloat16(acc[i][j][r] + bv);
        }
      }
    }
  } else {
#pragma unroll
    for (int j = 0; j < 4; j++) {
      const int col = cb0 + j * 16 + sub;
      const float bv = bias[col];
#pragma unroll
      for (int i = 0; i < 4; i++) {
        const int row = rb0 + i * 16 + quad * 4;
#pragma unroll
        for (int r = 0; r < 4; r++) {
          const float val = acc[i][j][r] + bv;
          ((float*)C0)[(size_t)(row + r) * N + col] = val;
        }
      }
    }
  }
}

// ---------------------------------------------------------------------------
// Fused Q GEMM + phi: qlog = x @ Wqf (B in bf16 hi/lo, 2-term MFMA), then
// per-row per-head softmax over the wave's 64 cols (= one head's 64 features):
//   e = exp(qlog - rowmax), sbuf = 1/(sum e*Df + eps*sum e); write e hi/lo.
// grid: (M/128, 8), block 256.
// ---------------------------------------------------------------------------
__global__ __launch_bounds__(256) void gemm_phi_kernel(
    const short* __restrict__ A, const short* __restrict__ Wh,
    const short* __restrict__ Wl, const float* __restrict__ bqf,
    const float* __restrict__ Df, short* __restrict__ ehi,
    short* __restrict__ elo, float* __restrict__ sbuf)
{
  constexpr int K = 1024;
  const int lane = threadIdx.x & 63;
  const int wid  = threadIdx.x >> 6;
  const int sub  = lane & 15;
  const int quad = lane >> 4;
  const int wr   = (wid >> 1) * 64;
  const int wc   = (wid & 1) * 64;
  const int row0 = blockIdx.x * 128;
  const int col0 = blockIdx.y * 128;

  __shared__ short As[128 * 64];
  __shared__ short Bhs[128 * 64];
  __shared__ short Bls[128 * 64];  // 48 KiB total

  f32x4_t acc[4][4] = {};

  const int srow = lane >> 3;
  for (int k0 = 0; k0 < K; k0 += 64) {
#pragma unroll
    for (int t = 0; t < 4; t++) {
      const int R   = wid * 32 + t * 8;
      const int row = R + srow;
      const int c   = (lane & 7) ^ (row & 7);
      load_lds_16B(A  + (size_t)(row0 + row) * K + k0 + c * 8, As  + R * 64);
      load_lds_16B(Wh + (size_t)(col0 + row) * K + k0 + c * 8, Bhs + R * 64);
      load_lds_16B(Wl + (size_t)(col0 + row) * K + k0 + c * 8, Bls + R * 64);
    }
    __syncthreads();

#pragma unroll
    for (int ks = 0; ks < 2; ks++) {
      bf16x8_t a[4], bh[4], bl[4];
#pragma unroll
      for (int i = 0; i < 4; i++) {
        const int ra = wr + i * 16 + sub;
        a[i] = *(const bf16x8_t*)(As + ra * 64 + (((ks * 4 + quad) ^ (ra & 7)) * 8));
        const int rb = wc + i * 16 + sub;
        bh[i] = *(const bf16x8_t*)(Bhs + rb * 64 + (((ks * 4 + quad) ^ (rb & 7)) * 8));
        bl[i] = *(const bf16x8_t*)(Bls + rb * 64 + (((ks * 4 + quad) ^ (rb & 7)) * 8));
      }
#pragma unroll
      for (int i = 0; i < 4; i++)
#pragma unroll
        for (int j = 0; j < 4; j++) {
          acc[i][j] = __builtin_amdgcn_mfma_f32_16x16x32_bf16(a[i], bh[j], acc[i][j], 0, 0, 0);
          acc[i][j] = __builtin_amdgcn_mfma_f32_16x16x32_bf16(a[i], bl[j], acc[i][j], 0, 0, 0);
        }
      __syncthreads();
    }
  }

  // epilogue: per-row softmax over this wave's 64 cols (one head)
  const int rb0 = row0 + wr;
  const int cb0 = col0 + wc;
  const int b   = row0 >> 12;
  const int h   = cb0 >> 6;
  float bv[4], Dl[4];
#pragma unroll
  for (int j = 0; j < 4; j++) {
    const int f = j * 16 + sub;
    bv[j] = bqf[h * 64 + f];
    Dl[j] = Df[(b * NH + h) * 64 + f];
  }
#pragma unroll
  for (int i = 0; i < 4; i++) {
#pragma unroll
    for (int r = 0; r < 4; r++) {
      float v[4];
#pragma unroll
      for (int j = 0; j < 4; j++) v[j] = acc[i][j][r] + bv[j];
      float mx = fmaxf(fmaxf(v[0], v[1]), fmaxf(v[2], v[3]));
#pragma unroll
      for (int o = 1; o < 16; o <<= 1) mx = fmaxf(mx, __shfl_xor(mx, o));
      float e[4], se = 0.f, dt = 0.f;
#pragma unroll
      for (int j = 0; j < 4; j++) {
        e[j] = __expf(v[j] - mx);
        se += e[j];
        dt = fmaf(e[j], Dl[j], dt);
      }
#pragma unroll
      for (int o = 1; o < 16; o <<= 1) { se += __shfl_xor(se, o); dt += __shfl_xor(dt, o); }

      const int row = rb0 + i * 16 + quad * 4 + r;  // global token index
      const size_t base = (size_t)row * DIMC + h * 64;
#pragma unroll
      for (int j = 0; j < 4; j++) {
        const __hip_bfloat16 hi = __float2bfloat16(e[j]);
        const float rem = e[j] - __bfloat162float(hi);
        const __hip_bfloat16 lo = __float2bfloat16(rem);
        ehi[base + j * 16 + sub] = *(const short*)&hi;
        elo[base + j * 16 + sub] = *(const short*)&lo;
      }
      if (sub == 0) sbuf[row * NH + h] = 1.f / (dt + FEPS * se);
    }
  }
}

// ---------------------------------------------------------------------------
// feat_gemm: out[tok][h*64+f] = sum_dh in[tok][h*64+dh] * W0[h][dh][f]
// in given as bf16 hi+lo split; 3-term hi/lo MFMA for ~fp32 precision.
// grid: (NTOK/128, NH), block 256; wave handles 32 tokens.
// ---------------------------------------------------------------------------
__global__ __launch_bounds__(256) void feat_gemm_kernel(
    const short* __restrict__ xhi, const short* __restrict__ xlo,
    const short* __restrict__ Whi, const short* __restrict__ Wlo,
    float* __restrict__ outlog)
{
  const int lane = threadIdx.x & 63, wid = threadIdx.x >> 6;
  const int sub = lane & 15, quad = lane >> 4;
  const int h = blockIdx.y;
  const int tok0 = blockIdx.x * 128 + wid * 32;
  const short* Bh = Whi + (size_t)h * 4096;
  const short* Bl = Wlo + (size_t)h * 4096;

  f32x4_t acc[2][4] = {};
#pragma unroll
  for (int ks = 0; ks < 2; ks++) {
    const int ko = ks * 32 + quad * 8;
    bf16x8_t ah[2], al[2], bh[4], bl[4];
#pragma unroll
    for (int i = 0; i < 2; i++) {
      const size_t base = (size_t)(tok0 + i * 16 + sub) * DIMC + h * 64 + ko;
      ah[i] = *(const bf16x8_t*)(xhi + base);
      al[i] = *(const bf16x8_t*)(xlo + base);
    }
#pragma unroll
    for (int j = 0; j < 4; j++) {
      const size_t base = (size_t)(j * 16 + sub) * 64 + ko;
      bh[j] = *(const bf16x8_t*)(Bh + base);
      bl[j] = *(const bf16x8_t*)(Bl + base);
    }
#pragma unroll
    for (int i = 0; i < 2; i++)
#pragma unroll
      for (int j = 0; j < 4; j++) {
        acc[i][j] = __builtin_amdgcn_mfma_f32_16x16x32_bf16(ah[i], bh[j], acc[i][j], 0, 0, 0);
        acc[i][j] = __builtin_amdgcn_mfma_f32_16x16x32_bf16(al[i], bh[j], acc[i][j], 0, 0, 0);
        acc[i][j] = __builtin_amdgcn_mfma_f32_16x16x32_bf16(ah[i], bl[j], acc[i][j], 0, 0, 0);
      }
  }
#pragma unroll
  for (int i = 0; i < 2; i++)
#pragma unroll
    for (int j = 0; j < 4; j++)
#pragma unroll
      for (int r = 0; r < 4; r++)
        outlog[(size_t)(tok0 + i * 16 + quad * 4 + r) * DIMC + h * 64 + j * 16 + sub] = acc[i][j][r];
}

// ---------------------------------------------------------------------------
// MFMA key summary. Per (b,h, chunk of 512 tokens):
//   w[l,f] = exp(klog[l,h,f] - 0.5*ksq[l,h])   (bf16 hi/lo in LDS, transposed)
//   N[f,d] += w^T @ vT  (MFMA, K = l), D[f] += w^T @ ones (same A-frags)
// grid: (NCHK=8, NH, NB), block 256 (4 waves; wave w owns f in [16w,16w+16)).
// ---------------------------------------------------------------------------
__global__ __launch_bounds__(256) void kv_summary_mfma(
    const float* __restrict__ klog, const float* __restrict__ ksq,
    const short* __restrict__ vT, float* __restrict__ pN, float* __restrict__ pD)
{
  const int chunk = blockIdx.x, h = blockIdx.y, b = blockIdx.z;
  const int tid  = threadIdx.x;
  const int lane = tid & 63, wid = tid >> 6;
  const int sub  = lane & 15, quad = lane >> 4;

  __shared__ short vTs[64 * 128];  // 16 KiB, row d = 256 B (16 x 16B chunks)
  __shared__ short wTh[64 * 128];  // 16 KiB, row f = 256 B
  __shared__ short wTl[64 * 128];  // 16 KiB

  f32x4_t accN[4] = {};
  f32x4_t accD = {};
  bf16x8_t bones;
#pragma unroll
  for (int e = 0; e < 8; e++) bones[e] = (sub == 0) ? (short)0x3F80 : (short)0;

  // w-phase mapping: thread pair per token (128 B of klog each)
  const int tw_t  = tid >> 1;          // 0..127 token-within-tile
  const int tw_f0 = (tid & 1) * 32;    // feature half

  const size_t vbase = ((size_t)((b * NH + h) * 64)) * (size_t)SL;
  const int fbase = (wid * 16 + sub) * 128;  // this wave's A-frag row base

  for (int it = 0; it < 4; ++it) {
    const int l0 = chunk * 512 + it * 128;

    // A) stage vT tile (swizzle already baked into global layout -> linear)
#pragma unroll
    for (int q = 0; q < 4; q++) {
      const int dbase = wid * 16 + q * 4;           // wave-uniform
      const int d = dbase + (lane >> 4);            // per-lane source row
      load_lds_16B(vT + vbase + (size_t)d * SL + l0 + (lane & 15) * 8,
                   vTs + dbase * 128);
    }

    // B) compute w = exp(klog - 0.5 ksq), write transposed hi/lo to LDS
    {
      const int tok = b * SL + l0 + tw_t;
      const float kq = 0.5f * ksq[tok * NH + h];
      const float* kr = klog + (size_t)tok * DIMC + h * 64 + tw_f0;
      f32x4_t kl[8];
#pragma unroll
      for (int v4 = 0; v4 < 8; v4++) kl[v4] = *(const f32x4_t*)(kr + v4 * 4);
#pragma unroll
      for (int v4 = 0; v4 < 8; v4++) {
#pragma unroll
        for (int e = 0; e < 4; e++) {
          const int f = tw_f0 + v4 * 4 + e;
          const float wv = __expf(kl[v4][e] - kq);
          const __hip_bfloat16 hi = __float2bfloat16(wv);
          const float rem = wv - __bfloat162float(hi);
          const __hip_bfloat16 lo = __float2bfloat16(rem);
          const int p = f * 128 + (((((tw_t >> 3) & 15) ^ (f & 15)) << 3) | (tw_t & 7));
          wTh[p] = *(const short*)&hi;
          wTl[p] = *(const short*)&lo;
        }
      }
    }
    __syncthreads();  // drains global_load_lds (vmcnt) + wT writes

    // C) MFMA: N[f,d] += w^T v ; D[f] += w^T 1
#pragma unroll
    for (int ks = 0; ks < 4; ks++) {
      const int ch = ks * 4 + quad;
      const bf16x8_t ah = *(const bf16x8_t*)(wTh + fbase + ((ch ^ sub) << 3));
      const bf16x8_t al = *(const bf16x8_t*)(wTl + fbase + ((ch ^ sub) << 3));
      accD = __builtin_amdgcn_mfma_f32_16x16x32_bf16(ah, bones, accD, 0, 0, 0);
      accD = __builtin_amdgcn_mfma_f32_16x16x32_bf16(al, bones, accD, 0, 0, 0);
#pragma unroll
      for (int j = 0; j < 4; j++) {
        const bf16x8_t bv = *(const bf16x8_t*)(vTs + (j * 16 + sub) * 128 + ((ch ^ sub) << 3));
        accN[j] = __builtin_amdgcn_mfma_f32_16x16x32_bf16(ah, bv, accN[j], 0, 0, 0);
        accN[j] = __builtin_amdgcn_mfma_f32_16x16x32_bf16(al, bv, accN[j], 0, 0, 0);
      }
    }
    __syncthreads();  // all reads done before next iteration restages
  }

  // write partials: pN[(bh,chunk)][f*64+d], pD[(bh,chunk)][f]
  const size_t pbase = (size_t)((b * NH + h) * NCHK + chunk);
#pragma unroll
  for (int j = 0; j < 4; j++)
#pragma unroll
    for (int r = 0; r < 4; r++)
      pN[pbase * 4096 + (wid * 16 + quad * 4 + r) * 64 + j * 16 + sub] = accN[j][r];
  if (sub == 0) {
#pragma unroll
    for (int r = 0; r < 4; r++)
      pD[pbase * 64 + wid * 16 + quad * 4 + r] = accD[r];
  }
}

// ---------------------------------------------------------------------------
// Combine chunk partials; write N^T (normalized, bf16 hi/lo, [d][f]) and
// normalized D (fp32). grid: (NB*NH, 16), block 256.
// ---------------------------------------------------------------------------
__global__ __launch_bounds__(256) void combine_nd_kernel(
    const float* __restrict__ pN, const float* __restrict__ pD,
    short* __restrict__ NfTh, short* __restrict__ NfTl, float* __restrict__ Df)
{
  const int bh = blockIdx.x, seg = blockIdx.y;
  __shared__ float sInv;
  float dsum = 0.f;
  if (threadIdx.x < 64) {
    for (int c = 0; c < NCHK; c++)
      dsum += pD[(size_t)(bh * NCHK + c) * 64 + threadIdx.x];
    float s = dsum;
#pragma unroll
    for (int o = 32; o; o >>= 1) s += __shfl_xor(s, o);
    if (threadIdx.x == 0) sInv = 1.f / s;
  }
  __syncthreads();
  const float inv = sInv;
  if (seg == 0 && threadIdx.x < 64) Df[bh * 64 + threadIdx.x] = dsum * inv;
  const int t = seg * 256 + threadIdx.x;   // t = f*64 + d
  float acc = 0.f;
  for (int c = 0; c < NCHK; c++)
    acc += pN[((size_t)(bh * NCHK + c)) * 4096 + t];
  const float val = acc * inv;
  const int f = t >> 6, d = t & 63;
  const __hip_bfloat16 hi = __float2bfloat16(val);
  const float rem = val - __bfloat162float(hi);
  const __hip_bfloat16 lo = __float2bfloat16(rem);
  NfTh[(size_t)bh * 4096 + d * 64 + f] = *(const short*)&hi;
  NfTl[(size_t)bh * 4096 + d * 64 + f] = *(const short*)&lo;
}

// ---------------------------------------------------------------------------
// ctx = (e @ N^T) * s : per (b,h) GEMM, M=tokens, N=64 d, K=64 f, 3-term hi/lo
// grid: (NTOK/128, NH), block 256; wave handles 32 tokens.
// ---------------------------------------------------------------------------
__global__ __launch_bounds__(256) void ctx_gemm_kernel(
    const short* __restrict__ ehi, const short* __restrict__ elo,
    const short* __restrict__ NfTh, const short* __restrict__ NfTl,
    const float* __restrict__ sbuf, __hip_bfloat16* __restrict__ ctx)
{
  const int lane = threadIdx.x & 63, wid = threadIdx.x >> 6;
  const int sub = lane & 15, quad = lane >> 4;
  const int h = blockIdx.y;
  const int tok0 = blockIdx.x * 128 + wid * 32;
  const int b = blockIdx.x >> 5;  // 32 x-blocks per batch (SL/128)
  const short* Bh = NfTh + ((size_t)(b * NH + h)) * 4096;
  const short* Bl = NfTl + ((size_t)(b * NH + h)) * 4096;

  f32x4_t acc[2][4] = {};
#pragma unroll
  for (int ks = 0; ks < 2; ks++) {
    const int ko = ks * 32 + quad * 8;
    bf16x8_t ah[2], al[2], bh[4], bl[4];
#pragma unroll
    for (int i = 0; i < 2; i++) {
      const size_t base = (size_t)(tok0 + i * 16 + sub) * DIMC + h * 64 + ko;
      ah[i] = *(const bf16x8_t*)(ehi + base);
      al[i] = *(const bf16x8_t*)(elo + base);
    }
#pragma unroll
    for (int j = 0; j < 4; j++) {
      const size_t base = (size_t)(j * 16 + sub) * 64 + ko;
      bh[j] = *(const bf16x8_t*)(Bh + base);
      bl[j] = *(const bf16x8_t*)(Bl + base);
    }
#pragma unroll
    for (int i = 0; i < 2; i++)
#pragma unroll
      for (int j = 0; j < 4; j++) {
        acc[i][j] = __builtin_amdgcn_mfma_f32_16x16x32_bf16(ah[i], bh[j], acc[i][j], 0, 0, 0);
        acc[i][j] = __builtin_amdgcn_mfma_f32_16x16x32_bf16(al[i], bh[j], acc[i][j], 0, 0, 0);
        acc[i][j] = __builtin_amdgcn_mfma_f32_16x16x32_bf16(ah[i], bl[j], acc[i][j], 0, 0, 0);
      }
  }
#pragma unroll
  for (int i = 0; i < 2; i++)
#pragma unroll
    for (int r = 0; r < 4; r++) {
      const int token = tok0 + i * 16 + quad * 4 + r;
      const float sv = sbuf[token * NH + h];
#pragma unroll
      for (int j = 0; j < 4; j++)
        ctx[(size_t)token * DIMC + h * 64 + j * 16 + sub] =
            __float2bfloat16(acc[i][j][r] * sv);
    }
}

// ---------------------------------------------------------------------------
extern "C" void kernel_launch(void* const* d_in, const int* in_sizes, int n_in,
                              void* d_out, int out_size, void* d_ws, size_t ws_size,
                              hipStream_t stream) {
  (void)in_sizes; (void)n_in; (void)out_size; (void)ws_size;
  const float* x   = (const float*)d_in[0];
  const float* Wq  = (const float*)d_in[1];
  const float* bq  = (const float*)d_in[2];
  const float* Wk  = (const float*)d_in[3];
  const float* bk  = (const float*)d_in[4];
  const float* Wv  = (const float*)d_in[5];
  const float* bv  = (const float*)d_in[6];
  const float* Wo  = (const float*)d_in[7];
  const float* bo  = (const float*)d_in[8];
  const float* Wrf = (const float*)d_in[9];
  float* out = (float*)d_out;

  constexpr size_t MiB = 1u << 20;
  constexpr size_t KiB = 1u << 10;
  constexpr size_t NTOK = (size_t)NB * SL;   // 16384
  constexpr size_t XN   = NTOK * DIMC;
  constexpr size_t WN   = (size_t)DIMC * DIMC;

  char* ws = (char*)d_ws;
  short* xb   = (short*)(ws);                        // bf16 x, 32 MiB; later ctxb
  short* Wkb  = (short*)(ws + 32 * MiB);
  short* Wvb  = (short*)(ws + 34 * MiB);
  short* Wob  = (short*)(ws + 36 * MiB);
  short* W0Th = (short*)(ws + 40 * MiB);             // 128 KiB
  short* W0Tl = (short*)(ws + 40 * MiB + 128 * KiB); // 128 KiB
  float* bqf  = (float*)(ws + 40 * MiB + 256 * KiB); // 4 KiB
  float* ksq  = (float*)(ws + 41 * MiB);             // 1 MiB
  float* sbuf = (float*)(ws + 42 * MiB);             // 1 MiB
  float* pD   = (float*)(ws + 43 * MiB);             // 128 KiB (64*8*64 f32)
  short* NfTh = (short*)(ws + 43 * MiB + 512 * KiB); // 512 KiB
  short* NfTl = (short*)(ws + 44 * MiB);             // 512 KiB
  float* Df   = (float*)(ws + 44 * MiB + 512 * KiB); // 16 KiB
  float* klog = (float*)(ws + 45 * MiB);             // 64 MiB [45..109)
  __hip_bfloat16* khi = (__hip_bfloat16*)(ws + 109 * MiB);  // 32 MiB
  __hip_bfloat16* klo = (__hip_bfloat16*)(ws + 141 * MiB);  // 32 MiB
  short* vTb  = (short*)(ws + 173 * MiB);            // 32 MiB, vT[(b,h,d)][swz l]
  // overlays (all precede their overwrite in stream order):
  float* pN   = (float*)(ws + 109 * MiB);            // 8 MiB over khi (dead after feat_gemm k)
  short* Wqfh = (short*)(ws + 173 * MiB);            // 2 MiB over vTb (dead after kv_summary)
  short* Wqfl = (short*)(ws + 175 * MiB);            // 2 MiB over vTb
  short* ehi  = (short*)(ws + 45 * MiB);             // over klog (dead after kv_summary)
  short* elo  = (short*)(ws + 77 * MiB);
  __hip_bfloat16* ctxb = (__hip_bfloat16*)xb;        // over xb (dead after gemm_phi)

  const dim3 blk(256);

  cast_f32_to_bf16<<<dim3(XN / 1024), blk, 0, stream>>>(x, xb, (int)XN);
  cast_f32_to_bf16<<<dim3(WN / 1024), blk, 0, stream>>>(Wk, Wkb, (int)WN);
  cast_f32_to_bf16<<<dim3(WN / 1024), blk, 0, stream>>>(Wv, Wvb, (int)WN);
  cast_f32_to_bf16<<<dim3(WN / 1024), blk, 0, stream>>>(Wo, Wob, (int)WN);
  prep_w0t_kernel<<<dim3(NH), blk, 0, stream>>>(Wrf, W0Th, W0Tl);

  const dim3 gg(NTOK / 128, DIMC / 128);
  gemm_lds_kernel<3><<<gg, blk, 0, stream>>>(xb, Wkb, bk, khi, klo, ksq);
  gemm_lds_kernel<5><<<gg, blk, 0, stream>>>(xb, Wvb, bv, vTb, nullptr, nullptr);

  feat_gemm_kernel<<<dim3(NTOK / 128, NH), blk, 0, stream>>>(
      (const short*)khi, (const short*)klo, W0Th, W0Tl, klog);

  kv_summary_mfma<<<dim3(NCHK, NH, NB), blk, 0, stream>>>(klog, ksq, vTb, pN, pD);
  // fuse_w0 AFTER kv_summary: Wqfh/Wqfl overlay the (now-dead) vTb region
  fuse_w0_kernel<<<dim3(NH, 16), blk, 0, stream>>>(Wq, bq, Wrf, Wqfh, Wqfl, bqf);
  combine_nd_kernel<<<dim3(NB * NH, 16), blk, 0, stream>>>(pN, pD, NfTh, NfTl, Df);

  gemm_phi_kernel<<<gg, blk, 0, stream>>>(xb, Wqfh, Wqfl, bqf, Df, ehi, elo, sbuf);
  ctx_gemm_kernel<<<dim3(NTOK / 128, NH), blk, 0, stream>>>(
      ehi, elo, NfTh, NfTl, sbuf, ctxb);

  gemm_lds_kernel<0><<<gg, blk, 0, stream>>>((const short*)ctxb, Wob, bo, out, nullptr, nullptr);
}

// Round 3
// 459.466 us; speedup vs baseline: 1.2559x; 1.0689x over previous
//
#include <hip/hip_runtime.h>
#include <hip/hip_bf16.h>

// Problem constants (fixed shapes from setup_inputs)
constexpr int NB   = 4;      // batch
constexpr int SL   = 4096;   // sequence length
constexpr int DIMC = 1024;   // model dim
constexpr int NH   = 16;     // heads
constexpr int DHC  = 64;     // head dim
constexpr int NFC  = 64;     // random features
constexpr int NCHK = 8;      // L-chunks for kv partial accumulation (512 tokens each)
constexpr float FEPS = 1e-6f;

typedef __attribute__((ext_vector_type(8))) short bf16x8_t;  // 8 bf16 (4 VGPRs)
typedef __attribute__((ext_vector_type(4))) float f32x4_t;   // MFMA accumulator
typedef __attribute__((ext_vector_type(4))) short s16x4_t;

// async global->LDS, 16 B per lane; LDS dest = wave-uniform base + lane*16
__device__ __forceinline__ void load_lds_16B(const short* g, short* l) {
  __builtin_amdgcn_global_load_lds(
      (__attribute__((address_space(1))) void*)(g),
      (__attribute__((address_space(3))) void*)(l), 16, 0, 0);
}

// ---------------------------------------------------------------------------
// fp32 -> bf16 cast (n divisible by 1024). 4 elements/thread.
// ---------------------------------------------------------------------------
__global__ __launch_bounds__(256) void cast_f32_to_bf16(
    const float* __restrict__ in, short* __restrict__ out, int n)
{
  const int i = (blockIdx.x * 256 + threadIdx.x) * 4;
  if (i >= n) return;
  const f32x4_t v = *(const f32x4_t*)(in + i);
  s16x4_t o;
#pragma unroll
  for (int j = 0; j < 4; j++) {
    __hip_bfloat16 h = __float2bfloat16(v[j]);
    o[j] = *(short*)&h;
  }
  *(s16x4_t*)(out + i) = o;
}

// ---------------------------------------------------------------------------
// W0 transposed per head, split bf16 hi/lo: W0T[h][f][dh]
// ---------------------------------------------------------------------------
__global__ __launch_bounds__(256) void prep_w0t_kernel(
    const float* __restrict__ Wrf, short* __restrict__ Whi, short* __restrict__ Wlo)
{
  const int h = blockIdx.x;
  for (int t = threadIdx.x; t < 4096; t += 256) {
    const int f = t >> 6, dh = t & 63;
    const float w = Wrf[(size_t)h * 4096 + dh * 64 + f];
    __hip_bfloat16 hi = __float2bfloat16(w);
    const float rem = w - __bfloat162float(hi);
    __hip_bfloat16 lo = __float2bfloat16(rem);
    Whi[(size_t)h * 4096 + t] = *(short*)&hi;
    Wlo[(size_t)h * 4096 + t] = *(short*)&lo;
  }
}

// ---------------------------------------------------------------------------
// Fused weight: Wqf[h*64+f][c] = sum_d Wq[h*64+d][c] * W0[h][d][f]  (fp32),
// split to bf16 hi/lo. bqf[h*64+f] = sum_d bq[h*64+d]*W0[h][d][f] (fp32).
// grid (NH, 16 c-blocks), block 256.
// ---------------------------------------------------------------------------
__global__ __launch_bounds__(256) void fuse_w0_kernel(
    const float* __restrict__ Wq, const float* __restrict__ bq,
    const float* __restrict__ Wrf,
    short* __restrict__ Wfh, short* __restrict__ Wfl, float* __restrict__ bqf)
{
  const int h = blockIdx.x, cb = blockIdx.y;
  __shared__ float sWq[64][64];  // [d][cc]
  __shared__ float sW0[64][64];  // [d][f]
  for (int idx = threadIdx.x; idx < 4096; idx += 256) {
    const int d = idx >> 6, e = idx & 63;
    sWq[d][e] = Wq[(size_t)(h * 64 + d) * 1024 + cb * 64 + e];
    sW0[d][e] = Wrf[(size_t)h * 4096 + d * 64 + e];
  }
  __syncthreads();
  for (int idx = threadIdx.x; idx < 4096; idx += 256) {
    const int f = idx >> 6, cc = idx & 63;
    float acc = 0.f;
#pragma unroll
    for (int d = 0; d < 64; d++) acc = fmaf(sWq[d][cc], sW0[d][f], acc);
    const __hip_bfloat16 hi = __float2bfloat16(acc);
    const float rem = acc - __bfloat162float(hi);
    const __hip_bfloat16 lo = __float2bfloat16(rem);
    Wfh[(size_t)(h * 64 + f) * 1024 + cb * 64 + cc] = *(const short*)&hi;
    Wfl[(size_t)(h * 64 + f) * 1024 + cb * 64 + cc] = *(const short*)&lo;
  }
  if (cb == 0 && threadIdx.x < 64) {
    const int f = threadIdx.x;
    float acc = 0.f;
#pragma unroll
    for (int d = 0; d < 64; d++) acc = fmaf(bq[h * 64 + d], sW0[d][f], acc);
    bqf[h * 64 + f] = acc;
  }
}

// ---------------------------------------------------------------------------
// LDS-staged GEMM (m97 structure): C[M,1024] = A[M,1024] @ W[1024,1024]^T + bias
// 128x128 block tile, BK=64, global_load_lds width=16, XOR-16B-chunk swizzle.
// MODE 0: fp32 C.
// MODE 3: C as bf16 hi (C0) + lo (C1) + ksq[row][head] = sum_d val^2
// MODE 5: transposed bf16 output vT[(b*NH+h)*64 + d][swz(l)] (operand-swapped
//         MFMA so the output-tile fragment is C^T; XOR-16B-chunk swizzle on the
//         l-within-128 position baked into the global layout so consumers can
//         global_load_lds linearly and ds_read_b128 conflict-free).
// grid: (M/128, 8), block 256 (4 waves; wave = 64x64 quadrant)
// ---------------------------------------------------------------------------
template <int MODE>
__global__ __launch_bounds__(256) void gemm_lds_kernel(
    const short* __restrict__ A, const short* __restrict__ W,
    const float* __restrict__ bias, void* __restrict__ C0,
    void* __restrict__ C1, float* __restrict__ Ks)
{
  constexpr int K = 1024, N = 1024;
  const int lane = threadIdx.x & 63;
  const int wid  = threadIdx.x >> 6;
  const int sub  = lane & 15;
  const int quad = lane >> 4;
  const int wr   = (wid >> 1) * 64;
  const int wc   = (wid & 1) * 64;
  const int row0 = blockIdx.x * 128;
  const int col0 = blockIdx.y * 128;

  __shared__ short As[128 * 64];  // 16 KiB, row = 128 B (8 x 16B chunks)
  __shared__ short Bs[128 * 64];

  f32x4_t acc[4][4] = {};

  const int srow = lane >> 3;
  for (int k0 = 0; k0 < K; k0 += 64) {
#pragma unroll
    for (int t = 0; t < 4; t++) {
      const int R   = wid * 32 + t * 8;
      const int row = R + srow;
      const int c   = (lane & 7) ^ (row & 7);
      load_lds_16B(A + (size_t)(row0 + row) * K + k0 + c * 8, As + R * 64);
      load_lds_16B(W + (size_t)(col0 + row) * K + k0 + c * 8, Bs + R * 64);
    }
    __syncthreads();

    bf16x8_t a[2][4], b[2][4];
#pragma unroll
    for (int ks = 0; ks < 2; ks++) {
#pragma unroll
      for (int i = 0; i < 4; i++) {
        const int ra = wr + i * 16 + sub;
        a[ks][i] = *(const bf16x8_t*)(As + ra * 64 + (((ks * 4 + quad) ^ (ra & 7)) * 8));
        const int rb = wc + i * 16 + sub;
        b[ks][i] = *(const bf16x8_t*)(Bs + rb * 64 + (((ks * 4 + quad) ^ (rb & 7)) * 8));
      }
    }
#pragma unroll
    for (int ks = 0; ks < 2; ks++)
#pragma unroll
      for (int i = 0; i < 4; i++)
#pragma unroll
        for (int j = 0; j < 4; j++) {
          if constexpr (MODE == 5)
            acc[i][j] = __builtin_amdgcn_mfma_f32_16x16x32_bf16(b[ks][j], a[ks][i], acc[i][j], 0, 0, 0);
          else
            acc[i][j] = __builtin_amdgcn_mfma_f32_16x16x32_bf16(a[ks][i], b[ks][j], acc[i][j], 0, 0, 0);
        }
    __syncthreads();
  }

  const int rb0 = row0 + wr;
  const int cb0 = col0 + wc;
  if constexpr (MODE == 3) {
    __hip_bfloat16* chi = (__hip_bfloat16*)C0;
    __hip_bfloat16* clo = (__hip_bfloat16*)C1;
    float s[4][4];
#pragma unroll
    for (int i = 0; i < 4; i++)
#pragma unroll
      for (int r = 0; r < 4; r++) s[i][r] = 0.f;
#pragma unroll
    for (int j = 0; j < 4; j++) {
      const int col = cb0 + j * 16 + sub;
      const float bv = bias[col];
#pragma unroll
      for (int i = 0; i < 4; i++) {
        const int row = rb0 + i * 16 + quad * 4;
#pragma unroll
        for (int r = 0; r < 4; r++) {
          const float val = acc[i][j][r] + bv;
          const __hip_bfloat16 hi = __float2bfloat16(val);
          const float rem = val - __bfloat162float(hi);
          chi[(size_t)(row + r) * N + col] = hi;
          clo[(size_t)(row + r) * N + col] = __float2bfloat16(rem);
          s[i][r] = fmaf(val, val, s[i][r]);
        }
      }
    }
    {
      const int head = cb0 >> 6;  // wave's 64 cols = exactly one head
#pragma unroll
      for (int o = 1; o < 16; o <<= 1)
#pragma unroll
        for (int i = 0; i < 4; i++)
#pragma unroll
          for (int r = 0; r < 4; r++) s[i][r] += __shfl_xor(s[i][r], o);
      if (sub == 0) {
#pragma unroll
        for (int i = 0; i < 4; i++)
#pragma unroll
          for (int r = 0; r < 4; r++)
            Ks[(size_t)(rb0 + i * 16 + quad * 4 + r) * NH + head] = s[i][r];
      }
    }
  } else if constexpr (MODE == 5) {
    // acc[i][j][r] (swapped mfma) = C[ row(token) = rb0+i*16+sub ]
    //                                [ col       = cb0+j*16+quad*4+r ]
    __hip_bfloat16* vT = (__hip_bfloat16*)C0;
    const int bb    = row0 >> 12;          // batch (4096 rows per batch)
    const int lbase = rb0 - (bb << 12);    // token-within-batch base
#pragma unroll
    for (int j = 0; j < 4; j++) {
#pragma unroll
      for (int r = 0; r < 4; r++) {
        const int col = cb0 + j * 16 + quad * 4 + r;
        const int h = col >> 6, d = col & 63;
        const float bv = bias[col];
        const size_t rowbase = ((size_t)((bb * NH + h) * 64 + d)) * (size_t)SL;
#pragma unroll
        for (int i = 0; i < 4; i++) {
          const int l = lbase + i * 16 + sub;
          const int pos = (l & ~127) | (((((l >> 3) & 15) ^ (d & 15)) << 3) | (l & 7));
          vT[rowbase + pos] = __float2bfloat16(acc[i][j][r] + bv);
        }
      }
    }
  } else {
#pragma unroll
    for (int j = 0; j < 4; j++) {
      const int col = cb0 + j * 16 + sub;
      const float bv = bias[col];
#pragma unroll
      for (int i = 0; i < 4; i++) {
        const int row = rb0 + i * 16 + quad * 4;
#pragma unroll
        for (int r = 0; r < 4; r++) {
          const float val = acc[i][j][r] + bv;
          ((float*)C0)[(size_t)(row + r) * N + col] = val;
        }
      }
    }
  }
}

// ---------------------------------------------------------------------------
// Fused Q GEMM + phi: qlog = x @ Wqf (B in bf16 hi/lo, 2-term MFMA), then
// per-row per-head softmax over the wave's 64 cols (= one head's 64 features):
//   e = exp(qlog - rowmax), sbuf = 1/(sum e*Df + eps*sum e); write e hi/lo.
// grid: (M/128, 8), block 256.
// ---------------------------------------------------------------------------
__global__ __launch_bounds__(256) void gemm_phi_kernel(
    const short* __restrict__ A, const short* __restrict__ Wh,
    const short* __restrict__ Wl, const float* __restrict__ bqf,
    const float* __restrict__ Df, short* __restrict__ ehi,
    short* __restrict__ elo, float* __restrict__ sbuf)
{
  constexpr int K = 1024;
  const int lane = threadIdx.x & 63;
  const int wid  = threadIdx.x >> 6;
  const int sub  = lane & 15;
  const int quad = lane >> 4;
  const int wr   = (wid >> 1) * 64;
  const int wc   = (wid & 1) * 64;
  const int row0 = blockIdx.x * 128;
  const int col0 = blockIdx.y * 128;

  __shared__ short As[128 * 64];
  __shared__ short Bhs[128 * 64];
  __shared__ short Bls[128 * 64];  // 48 KiB total

  f32x4_t acc[4][4] = {};

  const int srow = lane >> 3;
  for (int k0 = 0; k0 < K; k0 += 64) {
#pragma unroll
    for (int t = 0; t < 4; t++) {
      const int R   = wid * 32 + t * 8;
      const int row = R + srow;
      const int c   = (lane & 7) ^ (row & 7);
      load_lds_16B(A  + (size_t)(row0 + row) * K + k0 + c * 8, As  + R * 64);
      load_lds_16B(Wh + (size_t)(col0 + row) * K + k0 + c * 8, Bhs + R * 64);
      load_lds_16B(Wl + (size_t)(col0 + row) * K + k0 + c * 8, Bls + R * 64);
    }
    __syncthreads();

#pragma unroll
    for (int ks = 0; ks < 2; ks++) {
      bf16x8_t a[4], bh[4], bl[4];
#pragma unroll
      for (int i = 0; i < 4; i++) {
        const int ra = wr + i * 16 + sub;
        a[i] = *(const bf16x8_t*)(As + ra * 64 + (((ks * 4 + quad) ^ (ra & 7)) * 8));
        const int rb = wc + i * 16 + sub;
        bh[i] = *(const bf16x8_t*)(Bhs + rb * 64 + (((ks * 4 + quad) ^ (rb & 7)) * 8));
        bl[i] = *(const bf16x8_t*)(Bls + rb * 64 + (((ks * 4 + quad) ^ (rb & 7)) * 8));
      }
#pragma unroll
      for (int i = 0; i < 4; i++)
#pragma unroll
        for (int j = 0; j < 4; j++) {
          acc[i][j] = __builtin_amdgcn_mfma_f32_16x16x32_bf16(a[i], bh[j], acc[i][j], 0, 0, 0);
          acc[i][j] = __builtin_amdgcn_mfma_f32_16x16x32_bf16(a[i], bl[j], acc[i][j], 0, 0, 0);
        }
      __syncthreads();
    }
  }

  // epilogue: per-row softmax over this wave's 64 cols (one head)
  const int rb0 = row0 + wr;
  const int cb0 = col0 + wc;
  const int b   = row0 >> 12;
  const int h   = cb0 >> 6;
  float bv[4], Dl[4];
#pragma unroll
  for (int j = 0; j < 4; j++) {
    const int f = j * 16 + sub;
    bv[j] = bqf[h * 64 + f];
    Dl[j] = Df[(b * NH + h) * 64 + f];
  }
#pragma unroll
  for (int i = 0; i < 4; i++) {
#pragma unroll
    for (int r = 0; r < 4; r++) {
      float v[4];
#pragma unroll
      for (int j = 0; j < 4; j++) v[j] = acc[i][j][r] + bv[j];
      float mx = fmaxf(fmaxf(v[0], v[1]), fmaxf(v[2], v[3]));
#pragma unroll
      for (int o = 1; o < 16; o <<= 1) mx = fmaxf(mx, __shfl_xor(mx, o));
      float e[4], se = 0.f, dt = 0.f;
#pragma unroll
      for (int j = 0; j < 4; j++) {
        e[j] = __expf(v[j] - mx);
        se += e[j];
        dt = fmaf(e[j], Dl[j], dt);
      }
#pragma unroll
      for (int o = 1; o < 16; o <<= 1) { se += __shfl_xor(se, o); dt += __shfl_xor(dt, o); }

      const int row = rb0 + i * 16 + quad * 4 + r;  // global token index
      const size_t base = (size_t)row * DIMC + h * 64;
#pragma unroll
      for (int j = 0; j < 4; j++) {
        const __hip_bfloat16 hi = __float2bfloat16(e[j]);
        const float rem = e[j] - __bfloat162float(hi);
        const __hip_bfloat16 lo = __float2bfloat16(rem);
        ehi[base + j * 16 + sub] = *(const short*)&hi;
        elo[base + j * 16 + sub] = *(const short*)&lo;
      }
      if (sub == 0) sbuf[row * NH + h] = 1.f / (dt + FEPS * se);
    }
  }
}

// ---------------------------------------------------------------------------
// Fused key summary. Per (b,h, chunk of 512 tokens), per 128-token tile:
//   1) stage k hi/lo tile [128 tok][64 d] + vT tile + (once) W0T[h] hi/lo
//   2) klog = k @ W0T (3-term MFMA, fp32 acc)  [was feat_gemm, now in-kernel]
//   3) w = exp(klog - 0.5*ksq); transposed bf16 hi/lo into the SAME LDS
//      region as the k tile (dead after step 2; barrier-separated)
//   4) N[f,d] += w^T @ v (MFMA), D[f] += w^T @ ones
// grid: (NCHK=8, NH, NB), block 256 (4 waves; wave w owns f in [16w,16w+16)).
// ---------------------------------------------------------------------------
__global__ __launch_bounds__(256) void kv_fused_kernel(
    const short* __restrict__ khi, const short* __restrict__ klo,
    const short* __restrict__ W0h, const short* __restrict__ W0l,
    const float* __restrict__ ksq, const short* __restrict__ vT,
    float* __restrict__ pN, float* __restrict__ pD)
{
  const int chunk = blockIdx.x, h = blockIdx.y, b = blockIdx.z;
  const int tid  = threadIdx.x;
  const int lane = tid & 63, wid = tid >> 6;
  const int sub  = lane & 15, quad = lane >> 4;

  __shared__ short vTs[64 * 128];   // 16 KiB [d][tok-swz]
  __shared__ short w0hs[64 * 64];   // 8 KiB  [f][d-chunk-swz]
  __shared__ short w0ls[64 * 64];   // 8 KiB
  __shared__ short uh[128 * 64];    // 16 KiB: k-hi tile, then wT-hi [f][tok-swz]
  __shared__ short ul[128 * 64];    // 16 KiB: k-lo tile, then wT-lo

  f32x4_t accN[4] = {};
  f32x4_t accD = {};
  bf16x8_t bones;
#pragma unroll
  for (int e = 0; e < 8; e++) bones[e] = (sub == 0) ? (short)0x3F80 : (short)0;

  // stage W0T[h] hi/lo once (rows f, 64 d = 8 chunks, chunk-XOR swizzle)
#pragma unroll
  for (int t = 0; t < 2; t++) {
    const int R   = wid * 16 + t * 8;
    const int row = R + (lane >> 3);
    const int c   = (lane & 7) ^ (row & 7);
    load_lds_16B(W0h + (size_t)h * 4096 + row * 64 + c * 8, w0hs + R * 64);
    load_lds_16B(W0l + (size_t)h * 4096 + row * 64 + c * 8, w0ls + R * 64);
  }

  const size_t vbase = ((size_t)((b * NH + h) * 64)) * (size_t)SL;
  const int fbase = (wid * 16 + sub) * 128;  // wave's wT A-frag row base

  for (int it = 0; it < 4; ++it) {
    const int l0 = chunk * 512 + it * 128;

    // A) stage vT tile (swizzle baked into global layout -> linear)
#pragma unroll
    for (int q = 0; q < 4; q++) {
      const int dbase = wid * 16 + q * 4;           // wave-uniform
      const int d = dbase + (lane >> 4);            // per-lane source row
      load_lds_16B(vT + vbase + (size_t)d * SL + l0 + (lane & 15) * 8,
                   vTs + dbase * 128);
    }
    //    stage k hi/lo tile [128 tok][64 d], chunk-XOR swizzle
#pragma unroll
    for (int t = 0; t < 4; t++) {
      const int R   = wid * 32 + t * 8;
      const int row = R + (lane >> 3);
      const int c   = (lane & 7) ^ (row & 7);
      const size_t src = (size_t)(b * SL + l0 + row) * DIMC + h * 64 + c * 8;
      load_lds_16B(khi + src, uh + R * 64);
      load_lds_16B(klo + src, ul + R * 64);
    }
    __syncthreads();

    // B) klog tile = k @ W0T, 3-term hi/lo MFMA (fp32 acc)
    f32x4_t kacc[2][4] = {};
#pragma unroll
    for (int ks = 0; ks < 2; ks++) {
      bf16x8_t ah[2], al[2], b0[4], b1[4];
#pragma unroll
      for (int i = 0; i < 2; i++) {
        const int ra  = wid * 32 + i * 16 + sub;
        const int off = ra * 64 + (((ks * 4 + quad) ^ (ra & 7)) * 8);
        ah[i] = *(const bf16x8_t*)(uh + off);
        al[i] = *(const bf16x8_t*)(ul + off);
      }
#pragma unroll
      for (int j = 0; j < 4; j++) {
        const int rb  = j * 16 + sub;
        const int off = rb * 64 + (((ks * 4 + quad) ^ (rb & 7)) * 8);
        b0[j] = *(const bf16x8_t*)(w0hs + off);
        b1[j] = *(const bf16x8_t*)(w0ls + off);
      }
#pragma unroll
      for (int i = 0; i < 2; i++)
#pragma unroll
        for (int j = 0; j < 4; j++) {
          kacc[i][j] = __builtin_amdgcn_mfma_f32_16x16x32_bf16(ah[i], b0[j], kacc[i][j], 0, 0, 0);
          kacc[i][j] = __builtin_amdgcn_mfma_f32_16x16x32_bf16(al[i], b0[j], kacc[i][j], 0, 0, 0);
          kacc[i][j] = __builtin_amdgcn_mfma_f32_16x16x32_bf16(ah[i], b1[j], kacc[i][j], 0, 0, 0);
        }
    }
    __syncthreads();  // all k-tile reads done before aliasing as wT

    // C) w = exp(klog - 0.5*ksq); hi/lo split; transposed write into uh/ul
#pragma unroll
    for (int i = 0; i < 2; i++) {
#pragma unroll
      for (int r = 0; r < 4; r++) {
        const int tok = wid * 32 + i * 16 + quad * 4 + r;   // within tile
        const float kq = 0.5f * ksq[(size_t)(b * SL + l0 + tok) * NH + h];
#pragma unroll
        for (int j = 0; j < 4; j++) {
          const int f = j * 16 + sub;
          const float wv = __expf(kacc[i][j][r] - kq);
          const __hip_bfloat16 hi = __float2bfloat16(wv);
          const float rem = wv - __bfloat162float(hi);
          const __hip_bfloat16 lo = __float2bfloat16(rem);
          const int p = f * 128 + (((((tok >> 3) & 15) ^ (f & 15)) << 3) | (tok & 7));
          uh[p] = *(const short*)&hi;
          ul[p] = *(const short*)&lo;
        }
      }
    }
    __syncthreads();  // wT visible to all waves

    // D) MFMA: N[f,d] += w^T v ; D[f] += w^T 1
#pragma unroll
    for (int ks = 0; ks < 4; ks++) {
      const int ch = ks * 4 + quad;
      const bf16x8_t ah = *(const bf16x8_t*)(uh + fbase + ((ch ^ sub) << 3));
      const bf16x8_t al = *(const bf16x8_t*)(ul + fbase + ((ch ^ sub) << 3));
      accD = __builtin_amdgcn_mfma_f32_16x16x32_bf16(ah, bones, accD, 0, 0, 0);
      accD = __builtin_amdgcn_mfma_f32_16x16x32_bf16(al, bones, accD, 0, 0, 0);
#pragma unroll
      for (int j = 0; j < 4; j++) {
        const bf16x8_t bv = *(const bf16x8_t*)(vTs + (j * 16 + sub) * 128 + ((ch ^ sub) << 3));
        accN[j] = __builtin_amdgcn_mfma_f32_16x16x32_bf16(ah, bv, accN[j], 0, 0, 0);
        accN[j] = __builtin_amdgcn_mfma_f32_16x16x32_bf16(al, bv, accN[j], 0, 0, 0);
      }
    }
    __syncthreads();  // all reads done before next iteration restages
  }

  // write partials: pN[(bh,chunk)][f*64+d], pD[(bh,chunk)][f]
  const size_t pbase = (size_t)((b * NH + h) * NCHK + chunk);
#pragma unroll
  for (int j = 0; j < 4; j++)
#pragma unroll
    for (int r = 0; r < 4; r++)
      pN[pbase * 4096 + (wid * 16 + quad * 4 + r) * 64 + j * 16 + sub] = accN[j][r];
  if (sub == 0) {
#pragma unroll
    for (int r = 0; r < 4; r++)
      pD[pbase * 64 + wid * 16 + quad * 4 + r] = accD[r];
  }
}

// ---------------------------------------------------------------------------
// Combine chunk partials; write N^T (normalized, bf16 hi/lo, [d][f]) and
// normalized D (fp32). grid: (NB*NH, 16), block 256.
// ---------------------------------------------------------------------------
__global__ __launch_bounds__(256) void combine_nd_kernel(
    const float* __restrict__ pN, const float* __restrict__ pD,
    short* __restrict__ NfTh, short* __restrict__ NfTl, float* __restrict__ Df)
{
  const int bh = blockIdx.x, seg = blockIdx.y;
  __shared__ float sInv;
  float dsum = 0.f;
  if (threadIdx.x < 64) {
    for (int c = 0; c < NCHK; c++)
      dsum += pD[(size_t)(bh * NCHK + c) * 64 + threadIdx.x];
    float s = dsum;
#pragma unroll
    for (int o = 32; o; o >>= 1) s += __shfl_xor(s, o);
    if (threadIdx.x == 0) sInv = 1.f / s;
  }
  __syncthreads();
  const float inv = sInv;
  if (seg == 0 && threadIdx.x < 64) Df[bh * 64 + threadIdx.x] = dsum * inv;
  const int t = seg * 256 + threadIdx.x;   // t = f*64 + d
  float acc = 0.f;
  for (int c = 0; c < NCHK; c++)
    acc += pN[((size_t)(bh * NCHK + c)) * 4096 + t];
  const float val = acc * inv;
  const int f = t >> 6, d = t & 63;
  const __hip_bfloat16 hi = __float2bfloat16(val);
  const float rem = val - __bfloat162float(hi);
  const __hip_bfloat16 lo = __float2bfloat16(rem);
  NfTh[(size_t)bh * 4096 + d * 64 + f] = *(const short*)&hi;
  NfTl[(size_t)bh * 4096 + d * 64 + f] = *(const short*)&lo;
}

// ---------------------------------------------------------------------------
// ctx = (e @ N^T) * s : per (b,h) GEMM, M=tokens, N=64 d, K=64 f, 3-term hi/lo
// grid: (NTOK/128, NH), block 256; wave handles 32 tokens.
// ---------------------------------------------------------------------------
__global__ __launch_bounds__(256) void ctx_gemm_kernel(
    const short* __restrict__ ehi, const short* __restrict__ elo,
    const short* __restrict__ NfTh, const short* __restrict__ NfTl,
    const float* __restrict__ sbuf, __hip_bfloat16* __restrict__ ctx)
{
  const int lane = threadIdx.x & 63, wid = threadIdx.x >> 6;
  const int sub = lane & 15, quad = lane >> 4;
  const int h = blockIdx.y;
  const int tok0 = blockIdx.x * 128 + wid * 32;
  const int b = blockIdx.x >> 5;  // 32 x-blocks per batch (SL/128)
  const short* Bh = NfTh + ((size_t)(b * NH + h)) * 4096;
  const short* Bl = NfTl + ((size_t)(b * NH + h)) * 4096;

  f32x4_t acc[2][4] = {};
#pragma unroll
  for (int ks = 0; ks < 2; ks++) {
    const int ko = ks * 32 + quad * 8;
    bf16x8_t ah[2], al[2], bh[4], bl[4];
#pragma unroll
    for (int i = 0; i < 2; i++) {
      const size_t base = (size_t)(tok0 + i * 16 + sub) * DIMC + h * 64 + ko;
      ah[i] = *(const bf16x8_t*)(ehi + base);
      al[i] = *(const bf16x8_t*)(elo + base);
    }
#pragma unroll
    for (int j = 0; j < 4; j++) {
      const size_t base = (size_t)(j * 16 + sub) * 64 + ko;
      bh[j] = *(const bf16x8_t*)(Bh + base);
      bl[j] = *(const bf16x8_t*)(Bl + base);
    }
#pragma unroll
    for (int i = 0; i < 2; i++)
#pragma unroll
      for (int j = 0; j < 4; j++) {
        acc[i][j] = __builtin_amdgcn_mfma_f32_16x16x32_bf16(ah[i], bh[j], acc[i][j], 0, 0, 0);
        acc[i][j] = __builtin_amdgcn_mfma_f32_16x16x32_bf16(al[i], bh[j], acc[i][j], 0, 0, 0);
        acc[i][j] = __builtin_amdgcn_mfma_f32_16x16x32_bf16(ah[i], bl[j], acc[i][j], 0, 0, 0);
      }
  }
#pragma unroll
  for (int i = 0; i < 2; i++)
#pragma unroll
    for (int r = 0; r < 4; r++) {
      const int token = tok0 + i * 16 + quad * 4 + r;
      const float sv = sbuf[token * NH + h];
#pragma unroll
      for (int j = 0; j < 4; j++)
        ctx[(size_t)token * DIMC + h * 64 + j * 16 + sub] =
            __float2bfloat16(acc[i][j][r] * sv);
    }
}

// ---------------------------------------------------------------------------
extern "C" void kernel_launch(void* const* d_in, const int* in_sizes, int n_in,
                              void* d_out, int out_size, void* d_ws, size_t ws_size,
                              hipStream_t stream) {
  (void)in_sizes; (void)n_in; (void)out_size; (void)ws_size;
  const float* x   = (const float*)d_in[0];
  const float* Wq  = (const float*)d_in[1];
  const float* bq  = (const float*)d_in[2];
  const float* Wk  = (const float*)d_in[3];
  const float* bk  = (const float*)d_in[4];
  const float* Wv  = (const float*)d_in[5];
  const float* bv  = (const float*)d_in[6];
  const float* Wo  = (const float*)d_in[7];
  const float* bo  = (const float*)d_in[8];
  const float* Wrf = (const float*)d_in[9];
  float* out = (float*)d_out;

  constexpr size_t MiB = 1u << 20;
  constexpr size_t KiB = 1u << 10;
  constexpr size_t NTOK = (size_t)NB * SL;   // 16384
  constexpr size_t XN   = NTOK * DIMC;
  constexpr size_t WN   = (size_t)DIMC * DIMC;

  char* ws = (char*)d_ws;
  short* xb   = (short*)(ws);                        // bf16 x, 32 MiB; later ctxb
  short* Wkb  = (short*)(ws + 32 * MiB);
  short* Wvb  = (short*)(ws + 34 * MiB);
  short* Wob  = (short*)(ws + 36 * MiB);
  short* W0Th = (short*)(ws + 40 * MiB);             // 128 KiB
  short* W0Tl = (short*)(ws + 40 * MiB + 128 * KiB); // 128 KiB
  float* bqf  = (float*)(ws + 40 * MiB + 256 * KiB); // 4 KiB
  float* ksq  = (float*)(ws + 41 * MiB);             // 1 MiB
  float* sbuf = (float*)(ws + 42 * MiB);             // 1 MiB
  float* pD   = (float*)(ws + 43 * MiB);             // 128 KiB (64*8*64 f32)
  short* NfTh = (short*)(ws + 43 * MiB + 512 * KiB); // 512 KiB
  short* NfTl = (short*)(ws + 44 * MiB);             // 512 KiB
  float* Df   = (float*)(ws + 44 * MiB + 512 * KiB); // 16 KiB
  float* pN   = (float*)(ws + 45 * MiB);             // 8 MiB [45..53)
  __hip_bfloat16* khi = (__hip_bfloat16*)(ws + 109 * MiB);  // 32 MiB
  __hip_bfloat16* klo = (__hip_bfloat16*)(ws + 141 * MiB);  // 32 MiB
  short* vTb  = (short*)(ws + 173 * MiB);            // 32 MiB, vT[(b,h,d)][swz l]
  // overlays (all precede their overwrite in stream order):
  short* Wqfh = (short*)(ws + 173 * MiB);            // 2 MiB over vTb (dead after kv_fused)
  short* Wqfl = (short*)(ws + 175 * MiB);            // 2 MiB over vTb
  short* ehi  = (short*)(ws + 45 * MiB);             // over pN (dead after combine_nd)
  short* elo  = (short*)(ws + 77 * MiB);
  __hip_bfloat16* ctxb = (__hip_bfloat16*)xb;        // over xb (dead after gemm_phi)

  const dim3 blk(256);

  cast_f32_to_bf16<<<dim3(XN / 1024), blk, 0, stream>>>(x, xb, (int)XN);
  cast_f32_to_bf16<<<dim3(WN / 1024), blk, 0, stream>>>(Wk, Wkb, (int)WN);
  cast_f32_to_bf16<<<dim3(WN / 1024), blk, 0, stream>>>(Wv, Wvb, (int)WN);
  cast_f32_to_bf16<<<dim3(WN / 1024), blk, 0, stream>>>(Wo, Wob, (int)WN);
  prep_w0t_kernel<<<dim3(NH), blk, 0, stream>>>(Wrf, W0Th, W0Tl);

  const dim3 gg(NTOK / 128, DIMC / 128);
  gemm_lds_kernel<3><<<gg, blk, 0, stream>>>(xb, Wkb, bk, khi, klo, ksq);
  gemm_lds_kernel<5><<<gg, blk, 0, stream>>>(xb, Wvb, bv, vTb, nullptr, nullptr);

  kv_fused_kernel<<<dim3(NCHK, NH, NB), blk, 0, stream>>>(
      (const short*)khi, (const short*)klo, W0Th, W0Tl, ksq, vTb, pN, pD);
  // fuse_w0 AFTER kv_fused: Wqfh/Wqfl overlay the (now-dead) vTb region
  fuse_w0_kernel<<<dim3(NH, 16), blk, 0, stream>>>(Wq, bq, Wrf, Wqfh, Wqfl, bqf);
  combine_nd_kernel<<<dim3(NB * NH, 16), blk, 0, stream>>>(pN, pD, NfTh, NfTl, Df);

  gemm_phi_kernel<<<gg, blk, 0, stream>>>(xb, Wqfh, Wqfl, bqf, Df, ehi, elo, sbuf);
  ctx_gemm_kernel<<<dim3(NTOK / 128, NH), blk, 0, stream>>>(
      ehi, elo, NfTh, NfTl, sbuf, ctxb);

  gemm_lds_kernel<0><<<gg, blk, 0, stream>>>((const short*)ctxb, Wob, bo, out, nullptr, nullptr);
}